// Round 3
// baseline (1481.746 us; speedup 1.0000x reference)
//
#include <hip/hip_runtime.h>
#include <hip/hip_bf16.h>
#include <hip/hip_fp16.h>

// LieMoE: tokens, in_dim, hidden, out_dim, experts, topk
#define N_TOK 8192
#define DIM_D 1024
#define DIM_H 4096
#define DIM_O 1024
#define NEXP  8
#define TOPK  3

// Compact rows padded to 256 per expert: sum cnt = 24576, + 8*255 -> 26624.
#define CAP_ROWS  26624
#define MAX_TILES 104   // 26624 / 256

typedef _Float16 f16_t;
typedef _Float16 f16x4 __attribute__((ext_vector_type(4)));
typedef _Float16 f16x8 __attribute__((ext_vector_type(8)));
typedef float    floatx4 __attribute__((ext_vector_type(4)));

__device__ __forceinline__ void gld_lds16(const void* g, void* l) {
  __builtin_amdgcn_global_load_lds(
      (__attribute__((address_space(1))) void*)(void*)g,
      (__attribute__((address_space(3))) void*)l, 16, 0, 0);
}

// ---------------------------------------------------------------------------
// Gate: fp32 scores, softmax, top-3 (stable, first-index wins ties),
// renormalize; builds per-expert token lists. One wave per token.
// ---------------------------------------------------------------------------
__global__ __launch_bounds__(256) void gate_kernel(
    const float* __restrict__ x, const float* __restrict__ gw,
    const float* __restrict__ gb, float* __restrict__ wts,
    int* __restrict__ lists, int* __restrict__ cnt) {
  const int token = blockIdx.x * 4 + (threadIdx.x >> 6);
  const int lane = threadIdx.x & 63;
  float s[NEXP];
#pragma unroll
  for (int e = 0; e < NEXP; e++) s[e] = 0.f;
  const float* xr = x + (size_t)token * DIM_D;
  for (int d = lane; d < DIM_D; d += 64) {
    const float xv = xr[d];
    const float* g = gw + (size_t)d * NEXP;
#pragma unroll
    for (int e = 0; e < NEXP; e++) s[e] += xv * g[e];
  }
#pragma unroll
  for (int off = 32; off > 0; off >>= 1) {
#pragma unroll
    for (int e = 0; e < NEXP; e++) s[e] += __shfl_xor(s[e], off, 64);
  }
#pragma unroll
  for (int e = 0; e < NEXP; e++) s[e] += gb[e];

  float mx = s[0];
#pragma unroll
  for (int e = 1; e < NEXP; e++) mx = fmaxf(mx, s[e]);
  float p[NEXP];
  float den = 0.f;
#pragma unroll
  for (int e = 0; e < NEXP; e++) { p[e] = expf(s[e] - mx); den += p[e]; }

  bool sel[NEXP];
#pragma unroll
  for (int e = 0; e < NEXP; e++) sel[e] = false;
  for (int k = 0; k < TOPK; k++) {
    int bj = 0;
    float bv = -1e30f;
#pragma unroll
    for (int e = 0; e < NEXP; e++) {
      if (!sel[e] && s[e] > bv) { bv = s[e]; bj = e; }
    }
    sel[bj] = true;
  }
  float msum = 1e-8f * den;
#pragma unroll
  for (int e = 0; e < NEXP; e++) msum += sel[e] ? p[e] : 0.f;
  const float inv = 1.f / msum;
  if (lane < NEXP) {
    wts[(size_t)token * NEXP + lane] = sel[lane] ? p[lane] * inv : 0.f;
  }
  if (lane == 0) {
#pragma unroll
    for (int e = 0; e < NEXP; e++) {
      if (sel[e]) {
        const int pos = atomicAdd(&cnt[e], 1);
        lists[e * N_TOK + pos] = token;
      }
    }
  }
}

// ---------------------------------------------------------------------------
// Plan: 256-aligned prefix sums -> start rows; flat m-tile table (parallel).
// Entry: (expert << 16) | (tile_row0 >> 8)
// ---------------------------------------------------------------------------
__global__ __launch_bounds__(256) void plan_kernel(
    const int* __restrict__ cnt, int* __restrict__ start,
    int* __restrict__ table, int* __restrict__ total) {
  __shared__ int s_start[NEXP], s_tp[NEXP + 1];
  if (threadIdx.x == 0) {
    int r0 = 0, t = 0;
    for (int e = 0; e < NEXP; e++) {
      s_start[e] = r0;
      s_tp[e] = t;
      const int nt = (cnt[e] + 255) >> 8;
      t += nt;
      r0 += nt << 8;
      start[e] = s_start[e];
    }
    s_tp[NEXP] = t;
    total[0] = t;
  }
  __syncthreads();
  const int t = threadIdx.x;
  if (t < s_tp[NEXP]) {
    int e = 0;
    while (t >= s_tp[e + 1]) e++;
    table[t] = (e << 16) | ((s_start[e] >> 8) + (t - s_tp[e]));
  }
}

// ---------------------------------------------------------------------------
// Fill compact-row metadata: rowtok (token or -1 pad), roww (routing weight)
// ---------------------------------------------------------------------------
__global__ __launch_bounds__(256) void fill_kernel(
    const int* __restrict__ cnt, const int* __restrict__ start,
    const int* __restrict__ lists, const float* __restrict__ wts,
    int* __restrict__ rowtok, float* __restrict__ roww) {
  const int e = blockIdx.y;
  const int i = blockIdx.x * 256 + threadIdx.x;
  const int c = cnt[e];
  const int pad = (c + 255) & ~255;
  if (i >= pad) return;
  const int r = start[e] + i;
  if (i < c) {
    const int t = lists[e * N_TOK + i];
    rowtok[r] = t;
    roww[r] = wts[(size_t)t * NEXP + e];
  } else {
    rowtok[r] = -1;
    roww[r] = 0.f;
  }
}

// ---------------------------------------------------------------------------
// fp32 -> f16 elementwise (x)
// ---------------------------------------------------------------------------
__global__ __launch_bounds__(256) void cvt_f32_f16(
    const float* __restrict__ in, f16_t* __restrict__ out, int n4) {
  const int i = blockIdx.x * 256 + threadIdx.x;
  if (i >= n4) return;
  const float4 v = ((const float4*)in)[i];
  f16x4 o;
  o.x = (f16_t)v.x; o.y = (f16_t)v.y; o.z = (f16_t)v.z; o.w = (f16_t)v.w;
  ((f16x4*)out)[i] = o;
}

// ---------------------------------------------------------------------------
// fp32 [E][R][C] -> f16 [E][C][R] tiled transpose-convert (32x32 via LDS)
// ---------------------------------------------------------------------------
__global__ __launch_bounds__(256) void cvt_transpose(
    const float* __restrict__ in, f16_t* __restrict__ out, int R, int C) {
  __shared__ float tile[32][33];
  const int e = blockIdx.z;
  const int r0 = blockIdx.y * 32, c0 = blockIdx.x * 32;
  const int lc = threadIdx.x & 31, lr0 = threadIdx.x >> 5;
  const float* src = in + (size_t)e * R * C;
#pragma unroll
  for (int i = 0; i < 4; i++) {
    const int rr = lr0 + i * 8;
    tile[rr][lc] = src[(size_t)(r0 + rr) * C + c0 + lc];
  }
  __syncthreads();
  f16_t* dst = out + (size_t)e * C * R;
#pragma unroll
  for (int i = 0; i < 4; i++) {
    const int cc = lr0 + i * 8;
    dst[(size_t)(c0 + cc) * R + r0 + lc] = (f16_t)tile[lc][cc];
  }
}

// ---------------------------------------------------------------------------
// Merged sparse GEMM1, 256x128 tile (M x N), BK=32, 4 waves (2x2),
// wave tile 128x64 -> 8x4 fragments of 16x16x32 f16 MFMA.
// hg[r, n] = relu( xb[rowtok[r]] @ W1[e][:, cH+n] + b1 )
// ---------------------------------------------------------------------------
__global__ __launch_bounds__(256, 2) void gemm1_moe(
    const f16_t* __restrict__ xb, const f16_t* __restrict__ w1t,
    const float* __restrict__ b1, const int* __restrict__ rowtok,
    const int* __restrict__ table, const int* __restrict__ total,
    f16_t* __restrict__ hg, int Hc, int cH) {
  const int mt = blockIdx.y;
  if (mt >= total[0]) return;
  const int ent = table[mt];
  const int e = ent >> 16;
  const int r0 = (ent & 0xffff) << 8;
  const int n0 = blockIdx.x * 128;  // within chunk

  __shared__ __align__(16) f16_t Asm[256 * 32];
  __shared__ __align__(16) f16_t Bsm[128 * 32];
  const int tid = threadIdx.x;
  const int wave = tid >> 6, lane = tid & 63;
  const int q = lane >> 4, r = lane & 15;
  const int waveM = (wave >> 1) * 128, waveN = (wave & 1) * 64;

  const floatx4 zero = {0.f, 0.f, 0.f, 0.f};
  floatx4 acc[8][4];
#pragma unroll
  for (int mi = 0; mi < 8; mi++)
#pragma unroll
    for (int ni = 0; ni < 4; ni++) acc[mi][ni] = zero;

  const f16_t* BT = w1t + (size_t)e * DIM_H * DIM_D + (size_t)cH * DIM_D;

  // staging: A tile 256 rows x 4 16B-slots = 1024 slots (4/thread),
  //          B tile 128 rows x 4        =  512 slots (2/thread).
  const f16_t* Asrc[4];
  f16_t* AsmB[4];
#pragma unroll
  for (int j = 0; j < 4; j++) {
    const int s = tid + j * 256;
    const int row = s >> 2;
    const int gs = (s & 3) ^ ((row >> 1) & 3);
    const int tok = max(rowtok[r0 + row], 0);
    Asrc[j] = xb + (size_t)tok * DIM_D + gs * 8;
    AsmB[j] = &Asm[(wave * 64 + j * 256) * 8];
  }
  const f16_t* Bsrc[2];
  f16_t* BsmB[2];
#pragma unroll
  for (int j = 0; j < 2; j++) {
    const int s = tid + j * 256;
    const int row = s >> 2;
    const int gs = (s & 3) ^ ((row >> 1) & 3);
    Bsrc[j] = BT + (size_t)(n0 + row) * DIM_D + gs * 8;
    BsmB[j] = &Bsm[(wave * 64 + j * 256) * 8];
  }

  for (int k0 = 0; k0 < DIM_D; k0 += 32) {
#pragma unroll
    for (int j = 0; j < 4; j++) gld_lds16(Asrc[j] + k0, AsmB[j]);
#pragma unroll
    for (int j = 0; j < 2; j++) gld_lds16(Bsrc[j] + k0, BsmB[j]);
    __syncthreads();
    f16x8 af[8], bfr[4];
#pragma unroll
    for (int i = 0; i < 8; i++) {
      const int rowa = waveM + i * 16 + r;
      af[i] = *(const f16x8*)&Asm[rowa * 32 + ((q ^ ((rowa >> 1) & 3)) << 3)];
    }
#pragma unroll
    for (int i = 0; i < 4; i++) {
      const int rowb = waveN + i * 16 + r;
      bfr[i] = *(const f16x8*)&Bsm[rowb * 32 + ((q ^ ((rowb >> 1) & 3)) << 3)];
    }
#pragma unroll
    for (int mi = 0; mi < 8; mi++)
#pragma unroll
      for (int ni = 0; ni < 4; ni++)
        acc[mi][ni] = __builtin_amdgcn_mfma_f32_16x16x32_f16(
            af[mi], bfr[ni], acc[mi][ni], 0, 0, 0);
    __syncthreads();
  }

  // D-layout: col = lane&15, row = (lane>>4)*4 + reg
#pragma unroll
  for (int mi = 0; mi < 8; mi++)
#pragma unroll
    for (int ni = 0; ni < 4; ni++) {
      const int gcol = n0 + waveN + ni * 16 + r;
      const float bv = b1[(size_t)e * DIM_H + cH + gcol];
#pragma unroll
      for (int rr = 0; rr < 4; rr++) {
        const int grow = r0 + waveM + mi * 16 + q * 4 + rr;
        hg[(size_t)grow * Hc + gcol] = (f16_t)fmaxf(acc[mi][ni][rr] + bv, 0.f);
      }
    }
}

// ---------------------------------------------------------------------------
// Merged sparse GEMM2, 256x128 tile:
// out[rowtok[r]] += roww[r] * ( hg[r] @ W2[e][cH.., :] + b2 )
// ---------------------------------------------------------------------------
__global__ __launch_bounds__(256, 2) void gemm2_moe(
    const f16_t* __restrict__ hg, const f16_t* __restrict__ w2t,
    const float* __restrict__ b2, const int* __restrict__ rowtok,
    const float* __restrict__ roww, const int* __restrict__ table,
    const int* __restrict__ total, float* __restrict__ out, int Hc, int cH,
    int addBias) {
  const int mt = blockIdx.y;
  if (mt >= total[0]) return;
  const int ent = table[mt];
  const int e = ent >> 16;
  const int r0 = (ent & 0xffff) << 8;
  const int n0 = blockIdx.x * 128;  // O cols

  __shared__ __align__(16) f16_t Asm[256 * 32];
  __shared__ __align__(16) f16_t Bsm[128 * 32];
  const int tid = threadIdx.x;
  const int wave = tid >> 6, lane = tid & 63;
  const int q = lane >> 4, r = lane & 15;
  const int waveM = (wave >> 1) * 128, waveN = (wave & 1) * 64;

  const floatx4 zero = {0.f, 0.f, 0.f, 0.f};
  floatx4 acc[8][4];
#pragma unroll
  for (int mi = 0; mi < 8; mi++)
#pragma unroll
    for (int ni = 0; ni < 4; ni++) acc[mi][ni] = zero;

  const f16_t* BT = w2t + (size_t)e * DIM_O * DIM_H + cH;

  const f16_t* Asrc[4];
  f16_t* AsmB[4];
#pragma unroll
  for (int j = 0; j < 4; j++) {
    const int s = tid + j * 256;
    const int row = s >> 2;
    const int gs = (s & 3) ^ ((row >> 1) & 3);
    Asrc[j] = hg + (size_t)(r0 + row) * Hc + gs * 8;
    AsmB[j] = &Asm[(wave * 64 + j * 256) * 8];
  }
  const f16_t* Bsrc[2];
  f16_t* BsmB[2];
#pragma unroll
  for (int j = 0; j < 2; j++) {
    const int s = tid + j * 256;
    const int row = s >> 2;
    const int gs = (s & 3) ^ ((row >> 1) & 3);
    Bsrc[j] = BT + (size_t)(n0 + row) * DIM_H + gs * 8;
    BsmB[j] = &Bsm[(wave * 64 + j * 256) * 8];
  }

  for (int k0 = 0; k0 < Hc; k0 += 32) {
#pragma unroll
    for (int j = 0; j < 4; j++) gld_lds16(Asrc[j] + k0, AsmB[j]);
#pragma unroll
    for (int j = 0; j < 2; j++) gld_lds16(Bsrc[j] + k0, BsmB[j]);
    __syncthreads();
    f16x8 af[8], bfr[4];
#pragma unroll
    for (int i = 0; i < 8; i++) {
      const int rowa = waveM + i * 16 + r;
      af[i] = *(const f16x8*)&Asm[rowa * 32 + ((q ^ ((rowa >> 1) & 3)) << 3)];
    }
#pragma unroll
    for (int i = 0; i < 4; i++) {
      const int rowb = waveN + i * 16 + r;
      bfr[i] = *(const f16x8*)&Bsm[rowb * 32 + ((q ^ ((rowb >> 1) & 3)) << 3)];
    }
#pragma unroll
    for (int mi = 0; mi < 8; mi++)
#pragma unroll
      for (int ni = 0; ni < 4; ni++)
        acc[mi][ni] = __builtin_amdgcn_mfma_f32_16x16x32_f16(
            af[mi], bfr[ni], acc[mi][ni], 0, 0, 0);
    __syncthreads();
  }

#pragma unroll
  for (int mi = 0; mi < 8; mi++)
#pragma unroll
    for (int ni = 0; ni < 4; ni++) {
      const int gcol = n0 + waveN + ni * 16 + r;
      const float bv = addBias ? b2[(size_t)e * DIM_O + gcol] : 0.f;
#pragma unroll
      for (int rr = 0; rr < 4; rr++) {
        const int grow = r0 + waveM + mi * 16 + q * 4 + rr;
        const int t = rowtok[grow];
        if (t >= 0) {
          const float w = roww[grow];
          unsafeAtomicAdd(&out[(size_t)t * DIM_O + gcol],
                          w * (acc[mi][ni][rr] + bv));
        }
      }
    }
}

// ---------------------------------------------------------------------------
// launch
// ---------------------------------------------------------------------------
extern "C" void kernel_launch(void* const* d_in, const int* in_sizes, int n_in,
                              void* d_out, int out_size, void* d_ws, size_t ws_size,
                              hipStream_t stream) {
  const float* x      = (const float*)d_in[0];
  const float* gate_w = (const float*)d_in[1];
  const float* gate_b = (const float*)d_in[2];
  const float* w1     = (const float*)d_in[3];
  const float* b1     = (const float*)d_in[4];
  const float* w2     = (const float*)d_in[5];
  const float* b2     = (const float*)d_in[6];
  float* out = (float*)d_out;

  // workspace layout
  char* ws = (char*)d_ws;
  const size_t off_wts    = 0;          // 256 KB
  const size_t off_lists  = 0x40000;    // 256 KB
  const size_t off_cnt    = 0x80000;    // 512 B
  const size_t off_start  = 0x80200;    // 512 B
  const size_t off_total  = 0x80400;    // 512 B
  const size_t off_table  = 0x80600;    // 1 KB
  const size_t off_rowtok = 0x90000;    // 128 KB
  const size_t off_roww   = 0xB0000;    // 128 KB
  const size_t META       = 1 << 20;    // 1 MB reserved
  const size_t off_w1t = META;                                        // 64 MB
  const size_t off_w2t = off_w1t + (size_t)NEXP * DIM_H * DIM_D * 2;  // 64 MB
  const size_t off_xb  = off_w2t + (size_t)NEXP * DIM_O * DIM_H * 2;  // 16 MB
  const size_t off_hg  = off_xb + (size_t)N_TOK * DIM_D * 2;

  float* wts   = (float*)(ws + off_wts);
  int*   lists = (int*)(ws + off_lists);
  int*   cnt   = (int*)(ws + off_cnt);
  int*   start = (int*)(ws + off_start);
  int*   total = (int*)(ws + off_total);
  int*   table = (int*)(ws + off_table);
  int*   rowtok= (int*)(ws + off_rowtok);
  float* roww  = (float*)(ws + off_roww);
  f16_t* w1t   = (f16_t*)(ws + off_w1t);
  f16_t* w2t   = (f16_t*)(ws + off_w2t);
  f16_t* xb    = (f16_t*)(ws + off_xb);
  f16_t* hg    = (f16_t*)(ws + off_hg);

  // largest H-chunk that fits (ws_size constant across calls)
  int Hc = 512;
  for (int cand = 4096; cand >= 512; cand >>= 1) {
    if (off_hg + (size_t)CAP_ROWS * cand * 2 <= ws_size) { Hc = cand; break; }
  }
  const int nchunks = DIM_H / Hc;

  hipMemsetAsync(cnt, 0, 512, stream);
  hipMemsetAsync(d_out, 0, (size_t)out_size * sizeof(float), stream);

  gate_kernel<<<N_TOK / 4, 256, 0, stream>>>(x, gate_w, gate_b, wts, lists, cnt);
  plan_kernel<<<1, 256, 0, stream>>>(cnt, start, table, total);
  fill_kernel<<<dim3(N_TOK / 256, NEXP), 256, 0, stream>>>(
      cnt, start, lists, wts, rowtok, roww);

  const int n4 = N_TOK * DIM_D / 4;
  cvt_f32_f16<<<(n4 + 255) / 256, 256, 0, stream>>>(x, xb, n4);
  cvt_transpose<<<dim3(DIM_H / 32, DIM_D / 32, NEXP), 256, 0, stream>>>(
      w1, w1t, DIM_D, DIM_H);
  cvt_transpose<<<dim3(DIM_O / 32, DIM_H / 32, NEXP), 256, 0, stream>>>(
      w2, w2t, DIM_H, DIM_O);

  for (int c = 0; c < nchunks; c++) {
    const int cH = c * Hc;
    gemm1_moe<<<dim3(Hc / 128, MAX_TILES), 256, 0, stream>>>(
        xb, w1t, b1, rowtok, table, total, hg, Hc, cH);
    gemm2_moe<<<dim3(DIM_O / 128, MAX_TILES), 256, 0, stream>>>(
        hg, w2t, b2, rowtok, roww, table, total, out, Hc, cH, c == 0);
  }
}